// Round 2
// baseline (118.198 us; speedup 1.0000x reference)
//
#include <hip/hip_runtime.h>
#include <math.h>

#define DIM 3072
#define SEQ 8192
#define NROWS (3 * DIM)   // 9216 GEMV output rows

__device__ __forceinline__ float silu_f(float v) {
    return v / (1.0f + __expf(-v));
}

// One W row per wave (4 rows per 256-thread block). silu(emb) staged in LDS
// once per block (single barrier); wave-local shuffle reduction only.
__global__ __launch_bounds__(256, 4) void gemv3_kernel(
    const float* __restrict__ emb, const float* __restrict__ W,
    const float* __restrict__ b, float* __restrict__ shift,
    float* __restrict__ scale, float* __restrict__ gate)
{
    __shared__ float s[DIM];
    const int t = threadIdx.x;
    const float4* emb4 = (const float4*)emb;
    float4* s4 = (float4*)s;

    #pragma unroll
    for (int k = 0; k < 3; ++k) {
        int i = t + k * 256;                 // float4 index < 768
        float4 v = emb4[i];
        v.x = silu_f(v.x); v.y = silu_f(v.y);
        v.z = silu_f(v.z); v.w = silu_f(v.w);
        s4[i] = v;
    }
    __syncthreads();

    const int wid = t >> 6;
    const int lane = t & 63;
    const int row = blockIdx.x * 4 + wid;    // 0..NROWS-1, grid = NROWS/4
    const float4* w4 = (const float4*)(W + (size_t)row * DIM);

    float acc = 0.f;
    #pragma unroll
    for (int k = 0; k < 12; ++k) {
        int i = lane + 64 * k;
        float4 w = w4[i];
        float4 v = s4[i];
        acc += w.x * v.x + w.y * v.y + w.z * v.z + w.w * v.w;
    }

    #pragma unroll
    for (int off = 32; off > 0; off >>= 1)
        acc += __shfl_xor(acc, off, 64);

    if (lane == 0) {
        float e = acc + b[row];
        int i = row / 3;
        int r = row - 3 * i;
        if (r == 0)      shift[i] = e;
        else if (r == 1) scale[i] = e;
        else             gate[i]  = e;
    }
}

// One x row per wave (4 rows per block). Row held in 48 VGPRs; butterfly
// shuffle reduce gives every lane mean/rstd — no LDS, no barriers.
__global__ __launch_bounds__(256, 4) void ln_affine_kernel(
    const float* __restrict__ x, const float* __restrict__ shift,
    const float* __restrict__ scale, float* __restrict__ out)
{
    const int t = threadIdx.x;
    const int wid = t >> 6;
    const int lane = t & 63;
    const int row = blockIdx.x * 4 + wid;    // 0..SEQ-1, grid = SEQ/4
    const float4* x4 = (const float4*)(x + (size_t)row * DIM);
    float4* o4 = (float4*)(out + (size_t)row * DIM);
    const float4* sc4 = (const float4*)scale;
    const float4* sh4 = (const float4*)shift;

    float4 v[12];
    float sum = 0.f, sq = 0.f;
    #pragma unroll
    for (int k = 0; k < 12; ++k) {
        v[k] = x4[lane + 64 * k];
        sum += v[k].x + v[k].y + v[k].z + v[k].w;
        sq  += v[k].x * v[k].x + v[k].y * v[k].y + v[k].z * v[k].z + v[k].w * v[k].w;
    }

    #pragma unroll
    for (int off = 32; off > 0; off >>= 1) {
        sum += __shfl_xor(sum, off, 64);
        sq  += __shfl_xor(sq,  off, 64);
    }

    const float mean = sum * (1.0f / DIM);
    const float rstd = rsqrtf(sq * (1.0f / DIM) - mean * mean + 1e-6f);

    #pragma unroll 4
    for (int k = 0; k < 12; ++k) {
        int i = lane + 64 * k;
        float4 sc = sc4[i];
        float4 sh = sh4[i];
        float4 r;
        r.x = (v[k].x - mean) * rstd * sc.x + sh.x;
        r.y = (v[k].y - mean) * rstd * sc.y + sh.y;
        r.z = (v[k].z - mean) * rstd * sc.z + sh.z;
        r.w = (v[k].w - mean) * rstd * sc.w + sh.w;
        o4[i] = r;
    }
}

extern "C" void kernel_launch(void* const* d_in, const int* in_sizes, int n_in,
                              void* d_out, int out_size, void* d_ws, size_t ws_size,
                              hipStream_t stream) {
    const float* x   = (const float*)d_in[0];  // [1, 8192, 3072]
    const float* emb = (const float*)d_in[1];  // [1, 3072]
    const float* W   = (const float*)d_in[2];  // [9216, 3072]
    const float* b   = (const float*)d_in[3];  // [9216]
    float* out  = (float*)d_out;                       // [1,8192,3072] flat
    float* gate = out + (size_t)SEQ * DIM;             // [1,3072] appended
    float* shift = (float*)d_ws;                       // [3072]
    float* scale = shift + DIM;                        // [3072]

    gemv3_kernel<<<NROWS / 4, 256, 0, stream>>>(emb, W, b, shift, scale, gate);
    ln_affine_kernel<<<SEQ / 4, 256, 0, stream>>>(x, shift, scale, out);
}

// Round 3
// 67.393 us; speedup vs baseline: 1.7539x; 1.7539x over previous
//
#include <hip/hip_runtime.h>
#include <math.h>

#define DIM 3072
#define SEQ 8192
#define NROWS (3 * DIM)   // 9216 GEMV output rows

__device__ __forceinline__ float silu_f(float v) {
    return v / (1.0f + __expf(-v));
}

// One W row per wave (4 rows per 256-thread block). silu(emb) staged in LDS
// once per block (single barrier); wave-local shuffle reduction only.
__global__ __launch_bounds__(256, 4) void gemv3_kernel(
    const float* __restrict__ emb, const float* __restrict__ W,
    const float* __restrict__ b, float* __restrict__ shift,
    float* __restrict__ scale, float* __restrict__ gate)
{
    __shared__ float s[DIM];
    const int t = threadIdx.x;
    const float4* emb4 = (const float4*)emb;
    float4* s4 = (float4*)s;

    #pragma unroll
    for (int k = 0; k < 3; ++k) {
        int i = t + k * 256;                 // float4 index < 768
        float4 v = emb4[i];
        v.x = silu_f(v.x); v.y = silu_f(v.y);
        v.z = silu_f(v.z); v.w = silu_f(v.w);
        s4[i] = v;
    }
    __syncthreads();

    const int wid = t >> 6;
    const int lane = t & 63;
    const int row = blockIdx.x * 4 + wid;    // 0..NROWS-1, grid = NROWS/4
    const float4* w4 = (const float4*)(W + (size_t)row * DIM);

    float acc = 0.f;
    #pragma unroll
    for (int k = 0; k < 12; ++k) {
        int i = lane + 64 * k;
        float4 w = w4[i];
        float4 v = s4[i];
        acc += w.x * v.x + w.y * v.y + w.z * v.z + w.w * v.w;
    }

    #pragma unroll
    for (int off = 32; off > 0; off >>= 1)
        acc += __shfl_xor(acc, off, 64);

    if (lane == 0) {
        float e = acc + b[row];
        int i = row / 3;
        int r = row - 3 * i;
        if (r == 0)      shift[i] = e;
        else if (r == 1) scale[i] = e;
        else             gate[i]  = e;
    }
}

// One x row per wave (4 rows per block). Row held in 48 VGPRs; butterfly
// shuffle reduce gives every lane mean/rstd — no LDS, no barriers.
// NOTE: both loops FULLY unrolled so v[] has only compile-time indices
// (round-2 lesson: partial unroll sent v[] to scratch, 98us @ 14% HBM).
__global__ __launch_bounds__(256, 4) void ln_affine_kernel(
    const float* __restrict__ x, const float* __restrict__ shift,
    const float* __restrict__ scale, float* __restrict__ out)
{
    const int t = threadIdx.x;
    const int wid = t >> 6;
    const int lane = t & 63;
    const int row = blockIdx.x * 4 + wid;    // 0..SEQ-1, grid = SEQ/4
    const float4* x4 = (const float4*)(x + (size_t)row * DIM);
    float4* o4 = (float4*)(out + (size_t)row * DIM);
    const float4* sc4 = (const float4*)scale;
    const float4* sh4 = (const float4*)shift;

    float4 v[12];
    float sum = 0.f, sq = 0.f;
    #pragma unroll
    for (int k = 0; k < 12; ++k) {
        v[k] = x4[lane + 64 * k];
        sum += v[k].x + v[k].y + v[k].z + v[k].w;
        sq  += v[k].x * v[k].x + v[k].y * v[k].y + v[k].z * v[k].z + v[k].w * v[k].w;
    }

    #pragma unroll
    for (int off = 32; off > 0; off >>= 1) {
        sum += __shfl_xor(sum, off, 64);
        sq  += __shfl_xor(sq,  off, 64);
    }

    const float mean = sum * (1.0f / DIM);
    const float rstd = rsqrtf(sq * (1.0f / DIM) - mean * mean + 1e-6f);

    #pragma unroll
    for (int k = 0; k < 12; ++k) {
        int i = lane + 64 * k;
        float4 sc = sc4[i];
        float4 sh = sh4[i];
        float4 r;
        r.x = (v[k].x - mean) * rstd * sc.x + sh.x;
        r.y = (v[k].y - mean) * rstd * sc.y + sh.y;
        r.z = (v[k].z - mean) * rstd * sc.z + sh.z;
        r.w = (v[k].w - mean) * rstd * sc.w + sh.w;
        o4[i] = r;
    }
}

extern "C" void kernel_launch(void* const* d_in, const int* in_sizes, int n_in,
                              void* d_out, int out_size, void* d_ws, size_t ws_size,
                              hipStream_t stream) {
    const float* x   = (const float*)d_in[0];  // [1, 8192, 3072]
    const float* emb = (const float*)d_in[1];  // [1, 3072]
    const float* W   = (const float*)d_in[2];  // [9216, 3072]
    const float* b   = (const float*)d_in[3];  // [9216]
    float* out  = (float*)d_out;                       // [1,8192,3072] flat
    float* gate = out + (size_t)SEQ * DIM;             // [1,3072] appended
    float* shift = (float*)d_ws;                       // [3072]
    float* scale = shift + DIM;                        // [3072]

    gemv3_kernel<<<NROWS / 4, 256, 0, stream>>>(emb, W, b, shift, scale, gate);
    ln_affine_kernel<<<SEQ / 4, 256, 0, stream>>>(x, shift, scale, out);
}